// Round 4
// baseline (165.775 us; speedup 1.0000x reference)
//
#include <hip/hip_runtime.h>

// DeterministicEncoder: MLP encoder [M,2]->[M,64] + Laplace-kernel attention.
// exp(-|k-q|) factorizes: with context sorted by key, exclusive-prefix
// Lo[j] = sum_{i<j} e^{s_i} v_i and suffix Hi[j] = sum_{i>=j} e^{-s_i} v_i give
// out[n] = e^{-q} Lo[j_n] + e^{q} Hi[j_n], j_n = lower_bound(skey, q).
//
// Round 12: evidence says ~81us of the metric is two 256MiB harness poison
// fills inside the timed window; our kernels are only ~16us. Compress kernel
// time: merge round-11's K2a (scan, 64 blocks, 192 CUs idle) + K2b (query)
// into ONE 256-block kernel with a hand-rolled grid barrier (NOT cooperative
// launch: round 9 measured ~+20us for that path).
//   Deadlock-safety: 1024 thr + ~75KB LDS -> >=2 blocks/CU -> capacity 512
//   blocks >= 256 launched -> all blocks co-resident under ANY packing.
//   Visibility: __syncthreads drains stores (compiler emits vmcnt(0) before
//   s_barrier), release __threadfence + atomicAdd arrive, RMW spin + s_sleep,
//   acquire __threadfence after. K1 zeroes the counter (kernel-boundary
//   visibility); ws is re-poisoned per iteration but K1 re-zeroes each replay.
// Phase-1 scan and phase-2 query bodies are round-11's verified code verbatim.

#define H     16
#define OUTD  64
#define MM    8192                 // context/target count, fixed by harness
#define PAD(i) ((i) + ((i) >> 5)) // LDS bank padding
#define TILES 64
#define TROWS 128                  // rows per scan tile
#define RPT   8                    // rows per thread in scan (16 rg * 8 = 128)
#define NBLK  256                  // fused-kernel grid size

// ---------------------------------------------------------------- K1
// 256 blocks x 1024. Block b: rank+scatter rows [32b,32b+32), MLP same rows.
// Unchanged (verified) except: zeroes the grid-barrier counter for K2.
__global__ __launch_bounds__(1024) void rank_mlp_kernel(
    const float* __restrict__ xc, const float* __restrict__ yc,
    const float* __restrict__ W1, const float* __restrict__ b1,
    const float* __restrict__ W2, const float* __restrict__ b2,
    const float* __restrict__ W3, const float* __restrict__ b3,
    float* __restrict__ vS, float* __restrict__ skey,
    unsigned* __restrict__ ctr)
{
    __shared__ float sk[MM];          // all keys, 32 KB
    __shared__ int   red[32][4];      // [row][key-quarter] partial ranks
    __shared__ float sh2[32][H + 1];  // h2 per row, padded (17: coprime to 32)
    __shared__ int   rrk[32];         // rank of each of this block's 32 rows
    const int t = threadIdx.x;
    const int b = blockIdx.x;
    const int lane = t & 63, wid = t >> 6;

    if (b == 0 && t == 0) *ctr = 0u;  // barrier counter for K2 (replay-safe)

    for (int i = t; i < MM / 4; i += 1024)        // coalesced 16B staging
        ((float4*)sk)[i] = ((const float4*)xc)[i];
    __syncthreads();

    // rank: wave wid -> row-group rg = wid>>2 (8 rows), key-quarter qt = wid&3.
    {
        const int rg = wid >> 2, qt = wid & 3;
        const int m0 = b * 32 + rg * 8;
        float mk[8];
#pragma unroll
        for (int j = 0; j < 8; j++) mk[j] = sk[m0 + j];   // wave-uniform reads
        int cnt[8] = {0, 0, 0, 0, 0, 0, 0, 0};
#pragma unroll
        for (int ch = 0; ch < 8; ch++) {
            const int g = qt * 2048 + ch * 256 + lane * 4;
            const float4 k4 = *(const float4*)(sk + g);
#pragma unroll
            for (int j = 0; j < 8; j++) {
                const int m = m0 + j;
                const float k = mk[j];
                // strict total order on (key, index) -> rank is a permutation
                cnt[j] += (k4.x < k || (k4.x == k && (g + 0) < m)) ? 1 : 0;
                cnt[j] += (k4.y < k || (k4.y == k && (g + 1) < m)) ? 1 : 0;
                cnt[j] += (k4.z < k || (k4.z == k && (g + 2) < m)) ? 1 : 0;
                cnt[j] += (k4.w < k || (k4.w == k && (g + 3) < m)) ? 1 : 0;
            }
        }
#pragma unroll
        for (int j = 0; j < 8; j++) {            // in-wave reduction
            int v = cnt[j];
#pragma unroll
            for (int off = 32; off; off >>= 1) v += __shfl_down(v, off);
            if (lane == 0) red[rg * 8 + j][qt] = v;
        }
    }

    // MLP stage 1: h2 once per row (t<32).
    if (t < 32) {
        const int m = b * 32 + t;
        const float x = sk[m], y = yc[m];
        float h1[H];
#pragma unroll
        for (int j = 0; j < H; j++) {
            float a = x * W1[j] + y * W1[H + j] + b1[j];
            h1[j] = a > 0.f ? a : 0.f;
        }
#pragma unroll
        for (int j = 0; j < H; j++) {
            float a = b2[j];
#pragma unroll
            for (int i = 0; i < H; i++) a += h1[i] * W2[i * H + j];
            sh2[t][j] = a > 0.f ? a : 0.f;
        }
    }
    __syncthreads();

    // scatter (t<32): rank = sum of 4 partials, write sorted key + publish rank
    if (t < 32) {
        const int m = b * 32 + t;
        const int r = red[t][0] + red[t][1] + red[t][2] + red[t][3];
        skey[r] = sk[m];
        rrk[t] = r;
    }
    __syncthreads();   // stage 2 needs rrk

    // MLP stage 2: chp = t&31 lane-fast -> each half-wave writes one 256B
    // contiguous row vS[r][0..63] (float2 per lane). No false sharing: rows
    // are 256B-aligned and rank is a permutation (single writer per row).
    {
        const int chp = t & 31, ml = t >> 5;
        const int r = rrk[ml];
        const int cb = chp * 2;
        float a0 = b3[cb], a1 = b3[cb + 1];
#pragma unroll
        for (int i = 0; i < H; i++) {
            const float h = sh2[ml][i];          // half-wave-uniform broadcast
            const float2 w2 = ((const float2*)(W3 + i * OUTD))[chp];
            a0 += h * w2.x;
            a1 += h * w2.y;
        }
        ((float2*)(vS + (size_t)r * OUTD))[chp] = make_float2(a0, a1);
    }
}

// ---------------------------------------------------------------- K2 (fused)
// 256 blocks x 1024. Phase 1: blocks 0..63 scan one 128-row tile x 64 ch
// (round-11 scan_kernel body verbatim); all blocks stage sorted keys into LDS
// meanwhile. Grid barrier (arrive + RMW spin). Phase 2: round-11 query_kernel
// body verbatim (tile prefixes in LDS, wave-uniform searches, coalesced rows).
__global__ __launch_bounds__(1024) void scan_query_fused(
    const float* __restrict__ xt, const float* __restrict__ skey,
    const float* __restrict__ vS,
    float* __restrict__ LoT, float* __restrict__ HiT,
    float* __restrict__ tileLo, float* __restrict__ tileHi,
    unsigned* __restrict__ ctr, float* __restrict__ out)
{
    __shared__ float sk[PAD(MM) + 1];            // padded sorted keys, ~33KB
    __shared__ float tpLo [TILES + 1][OUTD];     // sum_{t'<t}  tileLo, 16.6KB
    __shared__ float tpHiA[TILES + 1][OUTD];     // sum_{t'>=t} tileHi, 16.6KB
    __shared__ float ldsLo[16][OUTD];            // scan partials, 4KB
    __shared__ float ldsHi[16][OUTD];            // scan partials, 4KB
    const int t = threadIdx.x;
    const int lane = t & 63, wid = t >> 6;
    const int bid = blockIdx.x;

    for (int i = t; i < MM / 4; i += 1024) {     // stage padded sorted keys
        const float4 k4 = ((const float4*)skey)[i];
        sk[PAD(4 * i + 0)] = k4.x; sk[PAD(4 * i + 1)] = k4.y;
        sk[PAD(4 * i + 2)] = k4.z; sk[PAD(4 * i + 3)] = k4.w;
    }

    // ---- phase 1: scan (blocks 0..63 only; block-uniform branch) ----
    if (bid < TILES) {
        const int c = t & 63, rg = t >> 6;
        const int i0 = bid * TROWS + rg * RPT;

        float wLo[RPT], wHi[RPT];
        float sLo = 0.f, sHi = 0.f;
#pragma unroll
        for (int r = 0; r < RPT; r++) {
            const int i = i0 + r;
            const float k = skey[i];                  // wave-uniform broadcast
            const float v = vS[(size_t)i * OUTD + c]; // coalesced 256B row
            const float eP = __expf(k), eN = __expf(-k);
            wLo[r] = eP * v;
            wHi[r] = eN * v;
            sLo += wLo[r];
            sHi += wHi[r];
        }
        ldsLo[rg][c] = sLo;
        ldsHi[rg][c] = sHi;
        __syncthreads();

        float preLo = 0.f, sufHi = 0.f;          // tile-local scan offsets
#pragma unroll
        for (int g = 0; g < 16; g++) {
            const float a = ldsLo[g][c];
            const float bb = ldsHi[g][c];
            preLo += (g < rg) ? a : 0.f;
            sufHi += (g > rg) ? bb : 0.f;
        }

        float run = preLo;                       // exclusive prefix (Lo)
#pragma unroll
        for (int r = 0; r < RPT; r++) {
            LoT[(size_t)(i0 + r) * OUTD + c] = run;   // coalesced 256B row
            run += wLo[r];
        }
        float run2 = sufHi;                      // inclusive suffix (Hi)
#pragma unroll
        for (int r = RPT - 1; r >= 0; r--) {
            run2 += wHi[r];
            HiT[(size_t)(i0 + r) * OUTD + c] = run2;  // coalesced 256B row
        }

        if (rg == 15) tileLo[bid * OUTD + c] = preLo + sLo;  // tile total
        if (rg == 0)  tileHi[bid * OUTD + c] = sufHi + sHi;  // tile total
    }

    // ---- grid barrier ----
    __syncthreads();          // drains every wave's global stores (vmcnt(0))
    if (t == 0) {
        __threadfence();      // release: make this block's writes device-visible
        atomicAdd(ctr, 1u);
        while (atomicAdd(ctr, 0u) < NBLK)        // device-scope RMW spin
            __builtin_amdgcn_s_sleep(8);
    }
    __syncthreads();
    __threadfence();          // acquire: invalidate stale cached lines

    // ---- phase 2: query (round-11 verified body) ----
    if (t < OUTD) {                              // per-channel tile prefixes
        float acc = 0.f;
        tpLo[0][t] = 0.f;
#pragma unroll 8
        for (int tt = 0; tt < TILES; tt++) {     // coalesced per step
            acc += tileLo[tt * OUTD + t];
            tpLo[tt + 1][t] = acc;
        }
        float acc2 = 0.f;
        tpHiA[TILES][t] = 0.f;
#pragma unroll 8
        for (int tt = TILES - 1; tt >= 0; tt--) {
            acc2 += tileHi[tt * OUTD + t];
            tpHiA[tt][t] = acc2;
        }
    }
    __syncthreads();

    // two interleaved wave-uniform 13-step lower_bounds (broadcast LDS reads)
    const int n0 = bid * 32 + wid * 2;
    const int n1 = n0 + 1;
    const float q0 = xt[n0], q1 = xt[n1];        // wave-uniform broadcasts
    int lo0 = 0, hi0v = MM, lo1 = 0, hi1v = MM;
#pragma unroll
    for (int s = 0; s < 13; s++) {               // 8192 = 2^13: exactly 13
        const int mid0 = (lo0 + hi0v) >> 1;
        const int mid1 = (lo1 + hi1v) >> 1;
        if (sk[PAD(mid0)] < q0) lo0 = mid0 + 1; else hi0v = mid0;
        if (sk[PAD(mid1)] < q1) lo1 = mid1 + 1; else hi1v = mid1;
    }

    // combine: Lo = tiles-before prefix + within-tile exclusive prefix;
    //          Hi = tiles-after suffix (tpHiA[t0+1]) + within-tile suffix.
    const int t0 = lo0 >> 7, t1 = lo1 >> 7;      // tile index (lo==MM -> 64)
    float L0 = tpLo[t0][lane], Hh0;
    float L1 = tpLo[t1][lane], Hh1;
    if (lo0 < MM) {                              // wave-uniform branch
        L0  += LoT[(size_t)lo0 * OUTD + lane];
        Hh0  = tpHiA[t0 + 1][lane] + HiT[(size_t)lo0 * OUTD + lane];
    } else {
        Hh0 = 0.f;                               // lo0 == MM: nothing above
    }
    if (lo1 < MM) {
        L1  += LoT[(size_t)lo1 * OUTD + lane];
        Hh1  = tpHiA[t1 + 1][lane] + HiT[(size_t)lo1 * OUTD + lane];
    } else {
        Hh1 = 0.f;
    }
    out[(size_t)n0 * OUTD + lane] = __expf(-q0) * L0 + __expf(q0) * Hh0;
    out[(size_t)n1 * OUTD + lane] = __expf(-q1) * L1 + __expf(q1) * Hh1;
}

extern "C" void kernel_launch(void* const* d_in, const int* in_sizes, int n_in,
                              void* d_out, int out_size, void* d_ws, size_t ws_size,
                              hipStream_t stream)
{
    const float* xc = (const float*)d_in[0];
    const float* yc = (const float*)d_in[1];
    const float* xt = (const float*)d_in[2];
    const float* W1 = (const float*)d_in[3];
    const float* b1 = (const float*)d_in[4];
    const float* W2 = (const float*)d_in[5];
    const float* b2 = (const float*)d_in[6];
    const float* W3 = (const float*)d_in[7];
    const float* b3 = (const float*)d_in[8];
    float* out = (float*)d_out;

    // workspace: vS [MM][64] (2MB) | skey [MM] (32KB) | LoT [MM][64] (2MB)
    //          | HiT [MM][64] (2MB) | tileLo [64][64] | tileHi [64][64] | ctr
    char* ws = (char*)d_ws;
    float*    vS     = (float*)ws;
    float*    skey   = (float*)(ws + (size_t)MM * OUTD * 4);
    float*    LoT    = (float*)(ws + (size_t)MM * OUTD * 4 + (size_t)MM * 4);
    float*    HiT    = LoT + (size_t)MM * OUTD;
    float*    tileLo = HiT + (size_t)MM * OUTD;
    float*    tileHi = tileLo + TILES * OUTD;
    unsigned* ctr    = (unsigned*)(tileHi + TILES * OUTD);

    rank_mlp_kernel<<<256, 1024, 0, stream>>>(xc, yc, W1, b1, W2, b2, W3, b3,
                                              vS, skey, ctr);
    scan_query_fused<<<NBLK, 1024, 0, stream>>>(xt, skey, vS, LoT, HiT,
                                                tileLo, tileHi, ctr, out);
}

// Round 5
// 97.818 us; speedup vs baseline: 1.6947x; 1.6947x over previous
//
#include <hip/hip_runtime.h>

// DeterministicEncoder: MLP encoder [M,2]->[M,64] + Laplace-kernel attention.
// exp(-|k-q|) factorizes: with context sorted by key, exclusive-prefix
// Lo[j] = sum_{i<j} e^{s_i} v_i and suffix Hi[j] = sum_{i>=j} e^{-s_i} v_i give
// out[n] = e^{-q} Lo[j_n] + e^{q} Hi[j_n], j_n = lower_bound(skey, q).
//
// Round 13: revert round-12's grid-barrier fusion (measured: fused kernel
// 85us, VALUBusy 2.7% -- device-scope fence + atomic spin across 8
// non-coherent XCD L2s costs 40-80us; a kernel boundary costs ~2us. Grid-wide
// intra-kernel sync is now twice-measured as a loss on MI355X). Back to the
// verified round-11 3-kernel structure with two kernel-time cuts:
//  1. K1 rank compare packed into u64: (sortable(key)<<13 | idx), one
//     v_cmp_lt_u64 + addc per element instead of ~5 VALU (float cmp x2 +
//     tiebreak logic). Same total order -> identical permutation.
//  2. K2a at 128 blocks (TROWS 128->64): 2x CUs busy in the scan. K2b tile
//     prefix arrays become [129][64]; LDS 99.8KB still fits.

#define H     16
#define OUTD  64
#define MM    8192                 // context/target count, fixed by harness
#define PAD(i) ((i) + ((i) >> 5)) // LDS bank padding
#define TILES 128
#define TROWS 64                   // rows per scan tile (MM/TILES)
#define RPT   4                    // rows per thread in scan (16 rg * 4 = 64)

// sortable mapping: monotone bijection float -> u32 (IEEE total order)
__device__ __forceinline__ unsigned long long packkey(float f, int idx) {
    unsigned b = __float_as_uint(f);
    unsigned s = (b >> 31) ? ~b : (b | 0x80000000u);
    return ((unsigned long long)s << 13) | (unsigned)idx;
}

// ---------------------------------------------------------------- K1
// 256 blocks x 1024. Block b: rank+scatter rows [32b,32b+32), MLP same rows.
// Rank inner loop now compares packed u64 keys (1 cmp + 1 addc per element).
__global__ __launch_bounds__(1024) void rank_mlp_kernel(
    const float* __restrict__ xc, const float* __restrict__ yc,
    const float* __restrict__ W1, const float* __restrict__ b1,
    const float* __restrict__ W2, const float* __restrict__ b2,
    const float* __restrict__ W3, const float* __restrict__ b3,
    float* __restrict__ vS, float* __restrict__ skey)
{
    __shared__ float sk[MM];                      // raw keys, 32 KB
    __shared__ unsigned long long sk64[MM];       // packed (key,idx), 64 KB
    __shared__ int   red[32][4];      // [row][key-quarter] partial ranks
    __shared__ float sh2[32][H + 1];  // h2 per row, padded (17: coprime to 32)
    __shared__ int   rrk[32];         // rank of each of this block's 32 rows
    const int t = threadIdx.x;
    const int b = blockIdx.x;
    const int lane = t & 63, wid = t >> 6;

    for (int i = t; i < MM / 4; i += 1024) {      // coalesced 16B staging
        const float4 k4 = ((const float4*)xc)[i];
        ((float4*)sk)[i] = k4;
        const int g = 4 * i;
        sk64[g + 0] = packkey(k4.x, g + 0);
        sk64[g + 1] = packkey(k4.y, g + 1);
        sk64[g + 2] = packkey(k4.z, g + 2);
        sk64[g + 3] = packkey(k4.w, g + 3);
    }
    __syncthreads();

    // rank: wave wid -> row-group rg = wid>>2 (8 rows), key-quarter qt = wid&3.
    // Strict total order on packed (key,idx): rank is a permutation; self
    // compares equal -> not counted.
    {
        const int rg = wid >> 2, qt = wid & 3;
        const int m0 = b * 32 + rg * 8;
        unsigned long long mp[8];
#pragma unroll
        for (int j = 0; j < 8; j++) mp[j] = sk64[m0 + j];  // wave-uniform
        int cnt[8] = {0, 0, 0, 0, 0, 0, 0, 0};
#pragma unroll
        for (int ch = 0; ch < 8; ch++) {
            const int g = qt * 2048 + ch * 256 + lane * 4;
            const unsigned long long p0 = sk64[g + 0];
            const unsigned long long p1 = sk64[g + 1];
            const unsigned long long p2 = sk64[g + 2];
            const unsigned long long p3 = sk64[g + 3];
#pragma unroll
            for (int j = 0; j < 8; j++) {
                cnt[j] += (p0 < mp[j]) ? 1 : 0;
                cnt[j] += (p1 < mp[j]) ? 1 : 0;
                cnt[j] += (p2 < mp[j]) ? 1 : 0;
                cnt[j] += (p3 < mp[j]) ? 1 : 0;
            }
        }
#pragma unroll
        for (int j = 0; j < 8; j++) {            // in-wave reduction
            int v = cnt[j];
#pragma unroll
            for (int off = 32; off; off >>= 1) v += __shfl_down(v, off);
            if (lane == 0) red[rg * 8 + j][qt] = v;
        }
    }

    // MLP stage 1: h2 once per row (t<32).
    if (t < 32) {
        const int m = b * 32 + t;
        const float x = sk[m], y = yc[m];
        float h1[H];
#pragma unroll
        for (int j = 0; j < H; j++) {
            float a = x * W1[j] + y * W1[H + j] + b1[j];
            h1[j] = a > 0.f ? a : 0.f;
        }
#pragma unroll
        for (int j = 0; j < H; j++) {
            float a = b2[j];
#pragma unroll
            for (int i = 0; i < H; i++) a += h1[i] * W2[i * H + j];
            sh2[t][j] = a > 0.f ? a : 0.f;
        }
    }
    __syncthreads();

    // scatter (t<32): rank = sum of 4 partials, write sorted key + publish rank
    if (t < 32) {
        const int m = b * 32 + t;
        const int r = red[t][0] + red[t][1] + red[t][2] + red[t][3];
        skey[r] = sk[m];
        rrk[t] = r;
    }
    __syncthreads();   // stage 2 needs rrk

    // MLP stage 2: chp = t&31 lane-fast -> each half-wave writes one 256B
    // contiguous row vS[r][0..63] (float2 per lane). No false sharing: rows
    // are 256B-aligned and rank is a permutation (single writer per row).
    {
        const int chp = t & 31, ml = t >> 5;
        const int r = rrk[ml];
        const int cb = chp * 2;
        float a0 = b3[cb], a1 = b3[cb + 1];
#pragma unroll
        for (int i = 0; i < H; i++) {
            const float h = sh2[ml][i];          // half-wave-uniform broadcast
            const float2 w2 = ((const float2*)(W3 + i * OUTD))[chp];
            a0 += h * w2.x;
            a1 += h * w2.y;
        }
        ((float2*)(vS + (size_t)r * OUTD))[chp] = make_float2(a0, a1);
    }
}

// ---------------------------------------------------------------- K2a (scan)
// 128 blocks x 1024. Block = one 64-row tile x ALL 64 channels.
// Thread (c = t&63, rg = t>>6) accumulates 4 rows serially; block-level LDS
// scan over the 16 row-groups; writes WITHIN-TILE exclusive prefix LoT[j][c]
// and suffix HiT[j][c] as coalesced 256B rows, plus per-tile totals.
__global__ __launch_bounds__(1024) void scan_kernel(
    const float* __restrict__ skey, const float* __restrict__ vS,
    float* __restrict__ LoT, float* __restrict__ HiT,
    float* __restrict__ tileLo, float* __restrict__ tileHi)
{
    __shared__ float ldsLo[16][OUTD];
    __shared__ float ldsHi[16][OUTD];
    const int t = threadIdx.x;
    const int c = t & 63, rg = t >> 6;
    const int tile = blockIdx.x;
    const int i0 = tile * TROWS + rg * RPT;

    float wLo[RPT], wHi[RPT];
    float sLo = 0.f, sHi = 0.f;
#pragma unroll
    for (int r = 0; r < RPT; r++) {
        const int i = i0 + r;
        const float k = skey[i];                 // wave-uniform broadcast load
        const float v = vS[(size_t)i * OUTD + c]; // coalesced 256B row
        const float eP = __expf(k), eN = __expf(-k);
        wLo[r] = eP * v;
        wHi[r] = eN * v;
        sLo += wLo[r];
        sHi += wHi[r];
    }
    ldsLo[rg][c] = sLo;
    ldsHi[rg][c] = sHi;
    __syncthreads();

    float preLo = 0.f, sufHi = 0.f;              // tile-local scan offsets
#pragma unroll
    for (int g = 0; g < 16; g++) {
        const float a = ldsLo[g][c];
        const float bb = ldsHi[g][c];
        preLo += (g < rg) ? a : 0.f;
        sufHi += (g > rg) ? bb : 0.f;
    }

    float run = preLo;                           // exclusive prefix (Lo)
#pragma unroll
    for (int r = 0; r < RPT; r++) {
        LoT[(size_t)(i0 + r) * OUTD + c] = run;  // coalesced 256B row
        run += wLo[r];
    }
    float run2 = sufHi;                          // inclusive suffix (Hi)
#pragma unroll
    for (int r = RPT - 1; r >= 0; r--) {
        run2 += wHi[r];
        HiT[(size_t)(i0 + r) * OUTD + c] = run2; // coalesced 256B row
    }

    if (rg == 15) tileLo[tile * OUTD + c] = preLo + sLo;  // tile total
    if (rg == 0)  tileHi[tile * OUTD + c] = sufHi + sHi;  // tile total
}

// ---------------------------------------------------------------- K2b (query)
// 256 blocks x 1024. Block b answers targets [32b, 32b+32), one wave per 2
// targets (interleaved searches), lane = channel. Cross-tile prefixes built
// once per block in LDS. All global reads/writes are coalesced 256B rows.
__global__ __launch_bounds__(1024) void query_kernel(
    const float* __restrict__ xt, const float* __restrict__ skey,
    const float* __restrict__ LoT, const float* __restrict__ HiT,
    const float* __restrict__ tileLo, const float* __restrict__ tileHi,
    float* __restrict__ out)
{
    __shared__ float sk[PAD(MM) + 1];            // padded sorted keys, ~33.8KB
    __shared__ float tpLo [TILES + 1][OUTD];     // sum_{t'<t}  tileLo, 33KB
    __shared__ float tpHiA[TILES + 1][OUTD];     // sum_{t'>=t} tileHi, 33KB
    const int t = threadIdx.x;
    const int lane = t & 63, wid = t >> 6;
    const int bid = blockIdx.x;

    for (int i = t; i < MM / 4; i += 1024) {     // stage padded sorted keys
        const float4 k4 = ((const float4*)skey)[i];
        sk[PAD(4 * i + 0)] = k4.x; sk[PAD(4 * i + 1)] = k4.y;
        sk[PAD(4 * i + 2)] = k4.z; sk[PAD(4 * i + 3)] = k4.w;
    }
    if (t < OUTD) {                              // per-channel tile prefixes
        float acc = 0.f;
        tpLo[0][t] = 0.f;
#pragma unroll 8
        for (int tt = 0; tt < TILES; tt++) {     // coalesced per step
            acc += tileLo[tt * OUTD + t];
            tpLo[tt + 1][t] = acc;
        }
        float acc2 = 0.f;
        tpHiA[TILES][t] = 0.f;
#pragma unroll 8
        for (int tt = TILES - 1; tt >= 0; tt--) {
            acc2 += tileHi[tt * OUTD + t];
            tpHiA[tt][t] = acc2;
        }
    }
    __syncthreads();

    // two interleaved wave-uniform 13-step lower_bounds (broadcast LDS reads)
    const int n0 = bid * 32 + wid * 2;
    const int n1 = n0 + 1;
    const float q0 = xt[n0], q1 = xt[n1];        // wave-uniform broadcasts
    int lo0 = 0, hi0v = MM, lo1 = 0, hi1v = MM;
#pragma unroll
    for (int s = 0; s < 13; s++) {               // 8192 = 2^13: exactly 13
        const int mid0 = (lo0 + hi0v) >> 1;
        const int mid1 = (lo1 + hi1v) >> 1;
        if (sk[PAD(mid0)] < q0) lo0 = mid0 + 1; else hi0v = mid0;
        if (sk[PAD(mid1)] < q1) lo1 = mid1 + 1; else hi1v = mid1;
    }

    // combine: Lo = tiles-before prefix + within-tile exclusive prefix;
    //          Hi = tiles-after suffix (tpHiA[t0+1]) + within-tile suffix.
    const int t0 = lo0 >> 6, t1 = lo1 >> 6;      // tile index (lo==MM -> 128)
    float L0 = tpLo[t0][lane], Hh0;
    float L1 = tpLo[t1][lane], Hh1;
    if (lo0 < MM) {                              // wave-uniform branch
        L0  += LoT[(size_t)lo0 * OUTD + lane];
        Hh0  = tpHiA[t0 + 1][lane] + HiT[(size_t)lo0 * OUTD + lane];
    } else {
        Hh0 = 0.f;                               // lo0 == MM: nothing above
    }
    if (lo1 < MM) {
        L1  += LoT[(size_t)lo1 * OUTD + lane];
        Hh1  = tpHiA[t1 + 1][lane] + HiT[(size_t)lo1 * OUTD + lane];
    } else {
        Hh1 = 0.f;
    }
    out[(size_t)n0 * OUTD + lane] = __expf(-q0) * L0 + __expf(q0) * Hh0;
    out[(size_t)n1 * OUTD + lane] = __expf(-q1) * L1 + __expf(q1) * Hh1;
}

extern "C" void kernel_launch(void* const* d_in, const int* in_sizes, int n_in,
                              void* d_out, int out_size, void* d_ws, size_t ws_size,
                              hipStream_t stream)
{
    const float* xc = (const float*)d_in[0];
    const float* yc = (const float*)d_in[1];
    const float* xt = (const float*)d_in[2];
    const float* W1 = (const float*)d_in[3];
    const float* b1 = (const float*)d_in[4];
    const float* W2 = (const float*)d_in[5];
    const float* b2 = (const float*)d_in[6];
    const float* W3 = (const float*)d_in[7];
    const float* b3 = (const float*)d_in[8];
    float* out = (float*)d_out;

    // workspace: vS [MM][64] (2MB) | skey [MM] (32KB) | LoT [MM][64] (2MB)
    //          | HiT [MM][64] (2MB) | tileLo [128][64] | tileHi [128][64]
    char* ws = (char*)d_ws;
    float* vS     = (float*)ws;
    float* skey   = (float*)(ws + (size_t)MM * OUTD * 4);
    float* LoT    = (float*)(ws + (size_t)MM * OUTD * 4 + (size_t)MM * 4);
    float* HiT    = LoT + (size_t)MM * OUTD;
    float* tileLo = HiT + (size_t)MM * OUTD;
    float* tileHi = tileLo + TILES * OUTD;

    rank_mlp_kernel<<<256, 1024, 0, stream>>>(xc, yc, W1, b1, W2, b2, W3, b3,
                                              vS, skey);
    scan_kernel<<<TILES, 1024, 0, stream>>>(skey, vS, LoT, HiT, tileLo, tileHi);
    query_kernel<<<256, 1024, 0, stream>>>(xt, skey, LoT, HiT, tileLo, tileHi,
                                           out);
}

// Round 6
// 92.806 us; speedup vs baseline: 1.7863x; 1.0540x over previous
//
#include <hip/hip_runtime.h>

// DeterministicEncoder: MLP encoder [M,2]->[M,64] + Laplace-kernel attention.
// exp(-|k-q|) factorizes: with context sorted by key, exclusive-prefix
// Lo[j] = sum_{i<j} e^{s_i} v_i and suffix Hi[j] = sum_{i>=j} e^{-s_i} v_i give
// out[n] = e^{-q} Lo[j_n] + e^{q} Hi[j_n], j_n = lower_bound(skey, q).
//
// Round 14: round-13's u64 rank was right in principle (5 VALU -> 2 per
// element) but wrong in implementation: 4x ds_read_b64 at 32B lane stride
// (~16-way bank conflict) and 96KB LDS (1 blk/CU). Fix both:
//  - ONE sk64 array (64KB -> 2 blk/CU); raw floats recovered by the exact
//    inverse of the sortable bijection (only needed for 32 rows/block).
//  - rank loop remapped: lane reads one lane-contiguous ulonglong2
//    (ds_read_b128, conflict-free) per iter; 16 iters x 16 cmp64+addc.
//    Same strict total order -> bit-identical permutation.
//  - K2b: PAD dropped (all search reads are wave-uniform broadcasts ->
//    conflicts impossible); keys staged as float4 ds_write_b128.
// K2a + combine logic: round-11 verbatim (verified). Grid-wide intra-kernel
// sync stays banned (rounds 9/12: 40-80us loss on 8 non-coherent XCD L2s).

#define H     16
#define OUTD  64
#define MM    8192                 // context/target count, fixed by harness
#define TILES 64
#define TROWS 128                  // rows per scan tile (MM/TILES)
#define RPT   8                    // rows per thread in scan (16 rg * 8 = 128)

// sortable mapping: monotone bijection float -> u32 (IEEE total order), then
// (s << 13) | idx gives a strict total order on (key, index).
__device__ __forceinline__ unsigned long long packkey(float f, int idx) {
    unsigned b = __float_as_uint(f);
    unsigned s = (b >> 31) ? ~b : (b | 0x80000000u);
    return ((unsigned long long)s << 13) | (unsigned)idx;
}
__device__ __forceinline__ float unpackkey(unsigned long long p) {
    unsigned s = (unsigned)(p >> 13);
    unsigned b = (s >> 31) ? (s ^ 0x80000000u) : ~s;
    return __uint_as_float(b);
}

// ---------------------------------------------------------------- K1
// 256 blocks x 1024. Block b: rank+scatter rows [32b,32b+32), MLP same rows.
__global__ __launch_bounds__(1024) void rank_mlp_kernel(
    const float* __restrict__ xc, const float* __restrict__ yc,
    const float* __restrict__ W1, const float* __restrict__ b1,
    const float* __restrict__ W2, const float* __restrict__ b2,
    const float* __restrict__ W3, const float* __restrict__ b3,
    float* __restrict__ vS, float* __restrict__ skey)
{
    __shared__ __align__(16) unsigned long long sk64[MM];  // packed keys, 64KB
    __shared__ int   red[32][4];      // [row][key-quarter] partial ranks
    __shared__ float sh2[32][H + 1];  // h2 per row, padded (17: coprime to 32)
    __shared__ int   rrk[32];         // rank of each of this block's 32 rows
    const int t = threadIdx.x;
    const int b = blockIdx.x;
    const int lane = t & 63, wid = t >> 6;

    // staging: thread t packs keys {g, g+1}, g = rr*2048 + 2t. float2 global
    // loads (8B coalesced); ulonglong2 LDS store at byte 16*(rr*1024+t):
    // lane-contiguous 16B -> conflict-free ds_write_b128.
#pragma unroll
    for (int rr = 0; rr < 4; rr++) {
        const int g = rr * 2048 + 2 * t;
        const float2 k2 = ((const float2*)xc)[rr * 1024 + t];
        ulonglong2 p;
        p.x = packkey(k2.x, g);
        p.y = packkey(k2.y, g + 1);
        ((ulonglong2*)sk64)[rr * 1024 + t] = p;
    }
    __syncthreads();

    // rank: wave wid -> row-group rg = wid>>2 (8 rows), key-quarter qt = wid&3.
    // Lane reads one lane-contiguous ulonglong2 per iter (ds_read_b128,
    // conflict-free); 2 keys x 8 rows x (v_cmp_lt_u64 + addc).
    {
        const int rg = wid >> 2, qt = wid & 3;
        const int m0 = b * 32 + rg * 8;
        unsigned long long mp[8];
#pragma unroll
        for (int j = 0; j < 8; j++) mp[j] = sk64[m0 + j];  // wave-uniform
        int cnt[8] = {0, 0, 0, 0, 0, 0, 0, 0};
#pragma unroll
        for (int it = 0; it < 16; it++) {
            const ulonglong2 p =
                ((const ulonglong2*)sk64)[qt * 1024 + it * 64 + lane];
#pragma unroll
            for (int j = 0; j < 8; j++) {
                cnt[j] += (p.x < mp[j]) ? 1 : 0;
                cnt[j] += (p.y < mp[j]) ? 1 : 0;
            }
        }
#pragma unroll
        for (int j = 0; j < 8; j++) {            // in-wave reduction
            int v = cnt[j];
#pragma unroll
            for (int off = 32; off; off >>= 1) v += __shfl_down(v, off);
            if (lane == 0) red[rg * 8 + j][qt] = v;
        }
    }

    // MLP stage 1: h2 once per row (t<32). x recovered exactly from sk64.
    if (t < 32) {
        const int m = b * 32 + t;
        const float x = unpackkey(sk64[m]), y = yc[m];
        float h1[H];
#pragma unroll
        for (int j = 0; j < H; j++) {
            float a = x * W1[j] + y * W1[H + j] + b1[j];
            h1[j] = a > 0.f ? a : 0.f;
        }
#pragma unroll
        for (int j = 0; j < H; j++) {
            float a = b2[j];
#pragma unroll
            for (int i = 0; i < H; i++) a += h1[i] * W2[i * H + j];
            sh2[t][j] = a > 0.f ? a : 0.f;
        }
    }
    __syncthreads();

    // scatter (t<32): rank = sum of 4 partials, write sorted key + publish rank
    if (t < 32) {
        const int m = b * 32 + t;
        const int r = red[t][0] + red[t][1] + red[t][2] + red[t][3];
        skey[r] = unpackkey(sk64[m]);
        rrk[t] = r;
    }
    __syncthreads();   // stage 2 needs rrk

    // MLP stage 2: chp = t&31 lane-fast -> each half-wave writes one 256B
    // contiguous row vS[r][0..63] (float2 per lane). No false sharing: rows
    // are 256B-aligned and rank is a permutation (single writer per row).
    {
        const int chp = t & 31, ml = t >> 5;
        const int r = rrk[ml];
        const int cb = chp * 2;
        float a0 = b3[cb], a1 = b3[cb + 1];
#pragma unroll
        for (int i = 0; i < H; i++) {
            const float h = sh2[ml][i];          // half-wave-uniform broadcast
            const float2 w2 = ((const float2*)(W3 + i * OUTD))[chp];
            a0 += h * w2.x;
            a1 += h * w2.y;
        }
        ((float2*)(vS + (size_t)r * OUTD))[chp] = make_float2(a0, a1);
    }
}

// ---------------------------------------------------------------- K2a (scan)
// 64 blocks x 1024. Block = one 128-row tile x ALL 64 channels.
// Thread (c = t&63, rg = t>>6) accumulates 8 rows serially; block-level LDS
// scan over the 16 row-groups; writes WITHIN-TILE exclusive prefix LoT[j][c]
// and suffix HiT[j][c] as coalesced 256B rows, plus per-tile totals.
__global__ __launch_bounds__(1024) void scan_kernel(
    const float* __restrict__ skey, const float* __restrict__ vS,
    float* __restrict__ LoT, float* __restrict__ HiT,
    float* __restrict__ tileLo, float* __restrict__ tileHi)
{
    __shared__ float ldsLo[16][OUTD];
    __shared__ float ldsHi[16][OUTD];
    const int t = threadIdx.x;
    const int c = t & 63, rg = t >> 6;
    const int tile = blockIdx.x;
    const int i0 = tile * TROWS + rg * RPT;

    float wLo[RPT], wHi[RPT];
    float sLo = 0.f, sHi = 0.f;
#pragma unroll
    for (int r = 0; r < RPT; r++) {
        const int i = i0 + r;
        const float k = skey[i];                 // wave-uniform broadcast load
        const float v = vS[(size_t)i * OUTD + c]; // coalesced 256B row
        const float eP = __expf(k), eN = __expf(-k);
        wLo[r] = eP * v;
        wHi[r] = eN * v;
        sLo += wLo[r];
        sHi += wHi[r];
    }
    ldsLo[rg][c] = sLo;
    ldsHi[rg][c] = sHi;
    __syncthreads();

    float preLo = 0.f, sufHi = 0.f;              // tile-local scan offsets
#pragma unroll
    for (int g = 0; g < 16; g++) {
        const float a = ldsLo[g][c];
        const float bb = ldsHi[g][c];
        preLo += (g < rg) ? a : 0.f;
        sufHi += (g > rg) ? bb : 0.f;
    }

    float run = preLo;                           // exclusive prefix (Lo)
#pragma unroll
    for (int r = 0; r < RPT; r++) {
        LoT[(size_t)(i0 + r) * OUTD + c] = run;  // coalesced 256B row
        run += wLo[r];
    }
    float run2 = sufHi;                          // inclusive suffix (Hi)
#pragma unroll
    for (int r = RPT - 1; r >= 0; r--) {
        run2 += wHi[r];
        HiT[(size_t)(i0 + r) * OUTD + c] = run2; // coalesced 256B row
    }

    if (rg == 15) tileLo[tile * OUTD + c] = preLo + sLo;  // tile total
    if (rg == 0)  tileHi[tile * OUTD + c] = sufHi + sHi;  // tile total
}

// ---------------------------------------------------------------- K2b (query)
// 256 blocks x 1024. Block b answers targets [32b, 32b+32), one wave per 2
// targets (interleaved searches), lane = channel. Cross-tile prefixes built
// once per block in LDS. All global reads/writes are coalesced 256B rows.
// No LDS padding: every sk read is wave-uniform (broadcast -> no conflicts).
__global__ __launch_bounds__(1024) void query_kernel(
    const float* __restrict__ xt, const float* __restrict__ skey,
    const float* __restrict__ LoT, const float* __restrict__ HiT,
    const float* __restrict__ tileLo, const float* __restrict__ tileHi,
    float* __restrict__ out)
{
    __shared__ float sk[MM];                     // sorted keys, 32KB
    __shared__ float tpLo [TILES + 1][OUTD];     // sum_{t'<t}  tileLo, 16.6KB
    __shared__ float tpHiA[TILES + 1][OUTD];     // sum_{t'>=t} tileHi, 16.6KB
    const int t = threadIdx.x;
    const int lane = t & 63, wid = t >> 6;
    const int bid = blockIdx.x;

    for (int i = t; i < MM / 4; i += 1024)       // float4 stage, conflict-free
        ((float4*)sk)[i] = ((const float4*)skey)[i];
    if (t < OUTD) {                              // per-channel tile prefixes
        float acc = 0.f;
        tpLo[0][t] = 0.f;
#pragma unroll 8
        for (int tt = 0; tt < TILES; tt++) {     // coalesced per step
            acc += tileLo[tt * OUTD + t];
            tpLo[tt + 1][t] = acc;
        }
        float acc2 = 0.f;
        tpHiA[TILES][t] = 0.f;
#pragma unroll 8
        for (int tt = TILES - 1; tt >= 0; tt--) {
            acc2 += tileHi[tt * OUTD + t];
            tpHiA[tt][t] = acc2;
        }
    }
    __syncthreads();

    // two interleaved wave-uniform 13-step lower_bounds (broadcast LDS reads)
    const int n0 = bid * 32 + wid * 2;
    const int n1 = n0 + 1;
    const float q0 = xt[n0], q1 = xt[n1];        // wave-uniform broadcasts
    int lo0 = 0, hi0v = MM, lo1 = 0, hi1v = MM;
#pragma unroll
    for (int s = 0; s < 13; s++) {               // 8192 = 2^13: exactly 13
        const int mid0 = (lo0 + hi0v) >> 1;
        const int mid1 = (lo1 + hi1v) >> 1;
        if (sk[mid0] < q0) lo0 = mid0 + 1; else hi0v = mid0;
        if (sk[mid1] < q1) lo1 = mid1 + 1; else hi1v = mid1;
    }

    // combine: Lo = tiles-before prefix + within-tile exclusive prefix;
    //          Hi = tiles-after suffix (tpHiA[t0+1]) + within-tile suffix.
    const int t0 = lo0 >> 7, t1 = lo1 >> 7;      // tile index (lo==MM -> 64)
    float L0 = tpLo[t0][lane], Hh0;
    float L1 = tpLo[t1][lane], Hh1;
    if (lo0 < MM) {                              // wave-uniform branch
        L0  += LoT[(size_t)lo0 * OUTD + lane];
        Hh0  = tpHiA[t0 + 1][lane] + HiT[(size_t)lo0 * OUTD + lane];
    } else {
        Hh0 = 0.f;                               // lo0 == MM: nothing above
    }
    if (lo1 < MM) {
        L1  += LoT[(size_t)lo1 * OUTD + lane];
        Hh1  = tpHiA[t1 + 1][lane] + HiT[(size_t)lo1 * OUTD + lane];
    } else {
        Hh1 = 0.f;
    }
    out[(size_t)n0 * OUTD + lane] = __expf(-q0) * L0 + __expf(q0) * Hh0;
    out[(size_t)n1 * OUTD + lane] = __expf(-q1) * L1 + __expf(q1) * Hh1;
}

extern "C" void kernel_launch(void* const* d_in, const int* in_sizes, int n_in,
                              void* d_out, int out_size, void* d_ws, size_t ws_size,
                              hipStream_t stream)
{
    const float* xc = (const float*)d_in[0];
    const float* yc = (const float*)d_in[1];
    const float* xt = (const float*)d_in[2];
    const float* W1 = (const float*)d_in[3];
    const float* b1 = (const float*)d_in[4];
    const float* W2 = (const float*)d_in[5];
    const float* b2 = (const float*)d_in[6];
    const float* W3 = (const float*)d_in[7];
    const float* b3 = (const float*)d_in[8];
    float* out = (float*)d_out;

    // workspace: vS [MM][64] (2MB) | skey [MM] (32KB) | LoT [MM][64] (2MB)
    //          | HiT [MM][64] (2MB) | tileLo [64][64] | tileHi [64][64]
    char* ws = (char*)d_ws;
    float* vS     = (float*)ws;
    float* skey   = (float*)(ws + (size_t)MM * OUTD * 4);
    float* LoT    = (float*)(ws + (size_t)MM * OUTD * 4 + (size_t)MM * 4);
    float* HiT    = LoT + (size_t)MM * OUTD;
    float* tileLo = HiT + (size_t)MM * OUTD;
    float* tileHi = tileLo + TILES * OUTD;

    rank_mlp_kernel<<<256, 1024, 0, stream>>>(xc, yc, W1, b1, W2, b2, W3, b3,
                                              vS, skey);
    scan_kernel<<<TILES, 1024, 0, stream>>>(skey, vS, LoT, HiT, tileLo, tileHi);
    query_kernel<<<256, 1024, 0, stream>>>(xt, skey, LoT, HiT, tileLo, tileHi,
                                           out);
}

// Round 7
// 89.538 us; speedup vs baseline: 1.8515x; 1.0365x over previous
//
#include <hip/hip_runtime.h>

// DeterministicEncoder: MLP encoder [M,2]->[M,64] + Laplace-kernel attention.
// exp(-|k-q|) factorizes: with context sorted by key, exclusive-prefix
// Lo[j] = sum_{i<j} e^{s_i} v_i and suffix Hi[j] = sum_{i>=j} e^{-s_i} v_i give
// out[n] = e^{-q} Lo[j_n] + e^{q} Hi[j_n], j_n = lower_bound(skey, q).
//
// Round 15: ledger says ~81us of the metric is two 256MiB harness poison
// fills (84% HBM peak -- already at roofline); our 3 kernels + gaps are
// ~12us. Two CU-utilization cuts on that slice, everything else verbatim
// from round 14 (92.8us best):
//  1. K2a TILES 64->128 (TROWS 64): scan runs on 128 blocks instead of 64
//     (round 13 bundled this with a K1 bank-conflict regression; confound
//     now removed).
//  2. K2b tile-prefix prologue parallelized: was 64 threads x TILES serial
//     iters (960 threads idle); now all 1024 threads as (c, g=t>>6): pass 1
//     sums 8 tile totals per group, pass 2 combines 16 group sums + local
//     running prefix. Required so TILES=128 doesn't double prologue cost.
// LDS K2b: 32KB sk + 2x[129][64] + 2x[16][64] = 106KB (1 blk/CU; grid==CUs
// so occupancy is unchanged). Grid-wide intra-kernel sync stays banned
// (rounds 9/12: 40-80us loss across 8 non-coherent XCD L2s).

#define H     16
#define OUTD  64
#define MM    8192                 // context/target count, fixed by harness
#define TILES 128
#define TROWS 64                   // rows per scan tile (MM/TILES)
#define RPT   4                    // rows per thread in scan (16 rg * 4 = 64)

// sortable mapping: monotone bijection float -> u32 (IEEE total order), then
// (s << 13) | idx gives a strict total order on (key, index).
__device__ __forceinline__ unsigned long long packkey(float f, int idx) {
    unsigned b = __float_as_uint(f);
    unsigned s = (b >> 31) ? ~b : (b | 0x80000000u);
    return ((unsigned long long)s << 13) | (unsigned)idx;
}
__device__ __forceinline__ float unpackkey(unsigned long long p) {
    unsigned s = (unsigned)(p >> 13);
    unsigned b = (s >> 31) ? (s ^ 0x80000000u) : ~s;
    return __uint_as_float(b);
}

// ---------------------------------------------------------------- K1
// 256 blocks x 1024. Block b: rank+scatter rows [32b,32b+32), MLP same rows.
// (round-14 verbatim -- verified at 92.8us)
__global__ __launch_bounds__(1024) void rank_mlp_kernel(
    const float* __restrict__ xc, const float* __restrict__ yc,
    const float* __restrict__ W1, const float* __restrict__ b1,
    const float* __restrict__ W2, const float* __restrict__ b2,
    const float* __restrict__ W3, const float* __restrict__ b3,
    float* __restrict__ vS, float* __restrict__ skey)
{
    __shared__ __align__(16) unsigned long long sk64[MM];  // packed keys, 64KB
    __shared__ int   red[32][4];      // [row][key-quarter] partial ranks
    __shared__ float sh2[32][H + 1];  // h2 per row, padded (17: coprime to 32)
    __shared__ int   rrk[32];         // rank of each of this block's 32 rows
    const int t = threadIdx.x;
    const int b = blockIdx.x;
    const int lane = t & 63, wid = t >> 6;

    // staging: thread t packs keys {g, g+1}, g = rr*2048 + 2t. float2 global
    // loads (8B coalesced); ulonglong2 LDS store at byte 16*(rr*1024+t):
    // lane-contiguous 16B -> conflict-free ds_write_b128.
#pragma unroll
    for (int rr = 0; rr < 4; rr++) {
        const int g = rr * 2048 + 2 * t;
        const float2 k2 = ((const float2*)xc)[rr * 1024 + t];
        ulonglong2 p;
        p.x = packkey(k2.x, g);
        p.y = packkey(k2.y, g + 1);
        ((ulonglong2*)sk64)[rr * 1024 + t] = p;
    }
    __syncthreads();

    // rank: wave wid -> row-group rg = wid>>2 (8 rows), key-quarter qt = wid&3.
    // Lane reads one lane-contiguous ulonglong2 per iter (ds_read_b128,
    // conflict-free); 2 keys x 8 rows x (v_cmp_lt_u64 + addc).
    {
        const int rg = wid >> 2, qt = wid & 3;
        const int m0 = b * 32 + rg * 8;
        unsigned long long mp[8];
#pragma unroll
        for (int j = 0; j < 8; j++) mp[j] = sk64[m0 + j];  // wave-uniform
        int cnt[8] = {0, 0, 0, 0, 0, 0, 0, 0};
#pragma unroll
        for (int it = 0; it < 16; it++) {
            const ulonglong2 p =
                ((const ulonglong2*)sk64)[qt * 1024 + it * 64 + lane];
#pragma unroll
            for (int j = 0; j < 8; j++) {
                cnt[j] += (p.x < mp[j]) ? 1 : 0;
                cnt[j] += (p.y < mp[j]) ? 1 : 0;
            }
        }
#pragma unroll
        for (int j = 0; j < 8; j++) {            // in-wave reduction
            int v = cnt[j];
#pragma unroll
            for (int off = 32; off; off >>= 1) v += __shfl_down(v, off);
            if (lane == 0) red[rg * 8 + j][qt] = v;
        }
    }

    // MLP stage 1: h2 once per row (t<32). x recovered exactly from sk64.
    if (t < 32) {
        const int m = b * 32 + t;
        const float x = unpackkey(sk64[m]), y = yc[m];
        float h1[H];
#pragma unroll
        for (int j = 0; j < H; j++) {
            float a = x * W1[j] + y * W1[H + j] + b1[j];
            h1[j] = a > 0.f ? a : 0.f;
        }
#pragma unroll
        for (int j = 0; j < H; j++) {
            float a = b2[j];
#pragma unroll
            for (int i = 0; i < H; i++) a += h1[i] * W2[i * H + j];
            sh2[t][j] = a > 0.f ? a : 0.f;
        }
    }
    __syncthreads();

    // scatter (t<32): rank = sum of 4 partials, write sorted key + publish rank
    if (t < 32) {
        const int m = b * 32 + t;
        const int r = red[t][0] + red[t][1] + red[t][2] + red[t][3];
        skey[r] = unpackkey(sk64[m]);
        rrk[t] = r;
    }
    __syncthreads();   // stage 2 needs rrk

    // MLP stage 2: chp = t&31 lane-fast -> each half-wave writes one 256B
    // contiguous row vS[r][0..63] (float2 per lane). No false sharing: rows
    // are 256B-aligned and rank is a permutation (single writer per row).
    {
        const int chp = t & 31, ml = t >> 5;
        const int r = rrk[ml];
        const int cb = chp * 2;
        float a0 = b3[cb], a1 = b3[cb + 1];
#pragma unroll
        for (int i = 0; i < H; i++) {
            const float h = sh2[ml][i];          // half-wave-uniform broadcast
            const float2 w2 = ((const float2*)(W3 + i * OUTD))[chp];
            a0 += h * w2.x;
            a1 += h * w2.y;
        }
        ((float2*)(vS + (size_t)r * OUTD))[chp] = make_float2(a0, a1);
    }
}

// ---------------------------------------------------------------- K2a (scan)
// 128 blocks x 1024. Block = one 64-row tile x ALL 64 channels.
// Thread (c = t&63, rg = t>>6) accumulates 4 rows serially; block-level LDS
// scan over the 16 row-groups; writes WITHIN-TILE exclusive prefix LoT[j][c]
// and suffix HiT[j][c] as coalesced 256B rows, plus per-tile totals.
__global__ __launch_bounds__(1024) void scan_kernel(
    const float* __restrict__ skey, const float* __restrict__ vS,
    float* __restrict__ LoT, float* __restrict__ HiT,
    float* __restrict__ tileLo, float* __restrict__ tileHi)
{
    __shared__ float ldsLo[16][OUTD];
    __shared__ float ldsHi[16][OUTD];
    const int t = threadIdx.x;
    const int c = t & 63, rg = t >> 6;
    const int tile = blockIdx.x;
    const int i0 = tile * TROWS + rg * RPT;

    float wLo[RPT], wHi[RPT];
    float sLo = 0.f, sHi = 0.f;
#pragma unroll
    for (int r = 0; r < RPT; r++) {
        const int i = i0 + r;
        const float k = skey[i];                 // wave-uniform broadcast load
        const float v = vS[(size_t)i * OUTD + c]; // coalesced 256B row
        const float eP = __expf(k), eN = __expf(-k);
        wLo[r] = eP * v;
        wHi[r] = eN * v;
        sLo += wLo[r];
        sHi += wHi[r];
    }
    ldsLo[rg][c] = sLo;
    ldsHi[rg][c] = sHi;
    __syncthreads();

    float preLo = 0.f, sufHi = 0.f;              // tile-local scan offsets
#pragma unroll
    for (int g = 0; g < 16; g++) {
        const float a = ldsLo[g][c];
        const float bb = ldsHi[g][c];
        preLo += (g < rg) ? a : 0.f;
        sufHi += (g > rg) ? bb : 0.f;
    }

    float run = preLo;                           // exclusive prefix (Lo)
#pragma unroll
    for (int r = 0; r < RPT; r++) {
        LoT[(size_t)(i0 + r) * OUTD + c] = run;  // coalesced 256B row
        run += wLo[r];
    }
    float run2 = sufHi;                          // inclusive suffix (Hi)
#pragma unroll
    for (int r = RPT - 1; r >= 0; r--) {
        run2 += wHi[r];
        HiT[(size_t)(i0 + r) * OUTD + c] = run2; // coalesced 256B row
    }

    if (rg == 15) tileLo[tile * OUTD + c] = preLo + sLo;  // tile total
    if (rg == 0)  tileHi[tile * OUTD + c] = sufHi + sHi;  // tile total
}

// ---------------------------------------------------------------- K2b (query)
// 256 blocks x 1024. Block b answers targets [32b, 32b+32), one wave per 2
// targets (interleaved searches), lane = channel. Cross-tile prefixes built
// by ALL 1024 threads (16 groups x 8 tiles, two-pass group scan). All global
// reads/writes are coalesced 256B rows. No LDS padding needed: search reads
// are wave-uniform broadcasts.
__global__ __launch_bounds__(1024) void query_kernel(
    const float* __restrict__ xt, const float* __restrict__ skey,
    const float* __restrict__ LoT, const float* __restrict__ HiT,
    const float* __restrict__ tileLo, const float* __restrict__ tileHi,
    float* __restrict__ out)
{
    __shared__ float sk[MM];                     // sorted keys, 32KB
    __shared__ float tpLo [TILES + 1][OUTD];     // sum_{t'<t}  tileLo, 33KB
    __shared__ float tpHiA[TILES + 1][OUTD];     // sum_{t'>=t} tileHi, 33KB
    __shared__ float gLo[16][OUTD];              // group sums, 4KB
    __shared__ float gHi[16][OUTD];              // group sums, 4KB
    const int t = threadIdx.x;
    const int lane = t & 63, wid = t >> 6;
    const int bid = blockIdx.x;

    for (int i = t; i < MM / 4; i += 1024)       // float4 stage, conflict-free
        ((float4*)sk)[i] = ((const float4*)skey)[i];

    // tile-prefix build, all threads: (c = t&63, g = t>>6), group g owns
    // tiles [8g, 8g+8). Pass 1: group totals. Pass 2: cross-group offset
    // (16 LDS reads) + local running prefix -> tpLo/tpHiA rows.
    {
        const int c = t & 63, g = t >> 6;
        float tl[8], th[8];
        float sL = 0.f, sH = 0.f;
#pragma unroll
        for (int k = 0; k < 8; k++) {            // coalesced 256B rows
            tl[k] = tileLo[(8 * g + k) * OUTD + c];
            th[k] = tileHi[(8 * g + k) * OUTD + c];
            sL += tl[k];
            sH += th[k];
        }
        gLo[g][c] = sL;
        gHi[g][c] = sH;
        __syncthreads();

        float preL = 0.f, sufH = 0.f;
#pragma unroll
        for (int gg = 0; gg < 16; gg++) {
            const float a = gLo[gg][c];
            const float bb = gHi[gg][c];
            preL += (gg < g) ? a : 0.f;
            sufH += (gg > g) ? bb : 0.f;
        }
        float run = preL;                        // exclusive prefix of tiles
#pragma unroll
        for (int k = 0; k < 8; k++) {
            tpLo[8 * g + k][c] = run;
            run += tl[k];
        }
        float run2 = sufH;                       // suffix incl. own tiles
#pragma unroll
        for (int k = 7; k >= 0; k--) {
            run2 += th[k];
            tpHiA[8 * g + k][c] = run2;
        }
        if (g == 15) {                           // boundaries (lo == MM)
            tpLo[TILES][c] = run;                // total Lo sum
            tpHiA[TILES][c] = 0.f;               // nothing above top tile
        }
    }
    __syncthreads();

    // two interleaved wave-uniform 13-step lower_bounds (broadcast LDS reads)
    const int n0 = bid * 32 + wid * 2;
    const int n1 = n0 + 1;
    const float q0 = xt[n0], q1 = xt[n1];        // wave-uniform broadcasts
    int lo0 = 0, hi0v = MM, lo1 = 0, hi1v = MM;
#pragma unroll
    for (int s = 0; s < 13; s++) {               // 8192 = 2^13: exactly 13
        const int mid0 = (lo0 + hi0v) >> 1;
        const int mid1 = (lo1 + hi1v) >> 1;
        if (sk[mid0] < q0) lo0 = mid0 + 1; else hi0v = mid0;
        if (sk[mid1] < q1) lo1 = mid1 + 1; else hi1v = mid1;
    }

    // combine: Lo = tiles-before prefix + within-tile exclusive prefix;
    //          Hi = tiles-after suffix (tpHiA[t0+1]) + within-tile suffix.
    const int t0 = lo0 >> 6, t1 = lo1 >> 6;      // tile index (lo==MM -> 128)
    float L0 = tpLo[t0][lane], Hh0;
    float L1 = tpLo[t1][lane], Hh1;
    if (lo0 < MM) {                              // wave-uniform branch
        L0  += LoT[(size_t)lo0 * OUTD + lane];
        Hh0  = tpHiA[t0 + 1][lane] + HiT[(size_t)lo0 * OUTD + lane];
    } else {
        Hh0 = 0.f;                               // lo0 == MM: nothing above
    }
    if (lo1 < MM) {
        L1  += LoT[(size_t)lo1 * OUTD + lane];
        Hh1  = tpHiA[t1 + 1][lane] + HiT[(size_t)lo1 * OUTD + lane];
    } else {
        Hh1 = 0.f;
    }
    out[(size_t)n0 * OUTD + lane] = __expf(-q0) * L0 + __expf(q0) * Hh0;
    out[(size_t)n1 * OUTD + lane] = __expf(-q1) * L1 + __expf(q1) * Hh1;
}

extern "C" void kernel_launch(void* const* d_in, const int* in_sizes, int n_in,
                              void* d_out, int out_size, void* d_ws, size_t ws_size,
                              hipStream_t stream)
{
    const float* xc = (const float*)d_in[0];
    const float* yc = (const float*)d_in[1];
    const float* xt = (const float*)d_in[2];
    const float* W1 = (const float*)d_in[3];
    const float* b1 = (const float*)d_in[4];
    const float* W2 = (const float*)d_in[5];
    const float* b2 = (const float*)d_in[6];
    const float* W3 = (const float*)d_in[7];
    const float* b3 = (const float*)d_in[8];
    float* out = (float*)d_out;

    // workspace: vS [MM][64] (2MB) | skey [MM] (32KB) | LoT [MM][64] (2MB)
    //          | HiT [MM][64] (2MB) | tileLo [128][64] | tileHi [128][64]
    char* ws = (char*)d_ws;
    float* vS     = (float*)ws;
    float* skey   = (float*)(ws + (size_t)MM * OUTD * 4);
    float* LoT    = (float*)(ws + (size_t)MM * OUTD * 4 + (size_t)MM * 4);
    float* HiT    = LoT + (size_t)MM * OUTD;
    float* tileLo = HiT + (size_t)MM * OUTD;
    float* tileHi = tileLo + TILES * OUTD;

    rank_mlp_kernel<<<256, 1024, 0, stream>>>(xc, yc, W1, b1, W2, b2, W3, b3,
                                              vS, skey);
    scan_kernel<<<TILES, 1024, 0, stream>>>(skey, vS, LoT, HiT, tileLo, tileHi);
    query_kernel<<<256, 1024, 0, stream>>>(xt, skey, LoT, HiT, tileLo, tileHi,
                                           out);
}